// Round 1
// baseline (2017.669 us; speedup 1.0000x reference)
//
#include <hip/hip_runtime.h>
#include <math.h>

#define N_NODES 20480
#define T_IN 128
#define F 256
#define HEADS 4
#define HID 64
#define NG 64
#define NCLS 4
#define NEG 0.2f
#define EPS 1e-5f

// ---------------- CSR build ----------------
__global__ void count_kernel(const int* __restrict__ src, const int* __restrict__ dst,
                             int E, int* __restrict__ counts) {
  int e = blockIdx.x * 256 + threadIdx.x;
  int tot = E + N_NODES;
  if (e >= tot) return;
  int d = (e < E) ? dst[e] : (e - E);
  atomicAdd(&counts[d], 1);
}

__global__ void scan1_kernel(const int* __restrict__ counts, int* __restrict__ ptr,
                             int* __restrict__ bsums) {
  __shared__ int s[256];
  int tid = threadIdx.x;
  int gid = blockIdx.x * 256 + tid;
  int v = counts[gid];
  s[tid] = v;
  __syncthreads();
  for (int off = 1; off < 256; off <<= 1) {
    int t = (tid >= off) ? s[tid - off] : 0;
    __syncthreads();
    s[tid] += t;
    __syncthreads();
  }
  ptr[gid] = s[tid] - v;               // block-local exclusive
  if (tid == 255) bsums[blockIdx.x] = s[255];
}

__global__ void scan2_kernel(int* __restrict__ bsums, int nb, int* __restrict__ ptr_last) {
  if (threadIdx.x == 0) {
    int acc = 0;
    for (int i = 0; i < nb; ++i) { int t = bsums[i]; bsums[i] = acc; acc += t; }
    *ptr_last = acc;
  }
}

__global__ void scan3_kernel(int* __restrict__ ptr, const int* __restrict__ bsums) {
  int gid = blockIdx.x * 256 + threadIdx.x;
  ptr[gid] += bsums[blockIdx.x];
}

__global__ void scatter_kernel(const int* __restrict__ src, const int* __restrict__ dst,
                               int E, const int* __restrict__ ptr, int* __restrict__ fill,
                               int* __restrict__ csr_src) {
  int e = blockIdx.x * 256 + threadIdx.x;
  int tot = E + N_NODES;
  if (e >= tot) return;
  int s, d;
  if (e < E) { s = src[e]; d = dst[e]; } else { s = d = e - E; }
  int pos = ptr[d] + atomicAdd(&fill[d], 1);
  csr_src[pos] = s;
}

// ---------------- GEMM: C[M,256] = A[M,K] @ B[K,256], fp32 ----------------
__global__ __launch_bounds__(256) void gemm_kernel(const float* __restrict__ A,
                                                   const float* __restrict__ B,
                                                   float* __restrict__ C, int M, int K) {
  __shared__ float sA[16][65];
  __shared__ float sB[16][65];
  int tid = threadIdx.x;
  int row0 = blockIdx.x * 64;
  int col0 = blockIdx.y * 64;
  int tx = tid & 15, ty = tid >> 4;
  int arow = tid >> 2;           // 0..63
  int acol = (tid & 3) * 4;      // 0,4,8,12
  int brow = tid >> 4;           // 0..15
  int bcol = (tid & 15) * 4;     // 0..60
  float acc[4][4] = {{0.f}};
  for (int kk = 0; kk < K; kk += 16) {
    float4 av = *(const float4*)(&A[(size_t)(row0 + arow) * K + kk + acol]);
    float4 bv = *(const float4*)(&B[(size_t)(kk + brow) * F + col0 + bcol]);
    sA[acol + 0][arow] = av.x;
    sA[acol + 1][arow] = av.y;
    sA[acol + 2][arow] = av.z;
    sA[acol + 3][arow] = av.w;
    sB[brow][bcol + 0] = bv.x;
    sB[brow][bcol + 1] = bv.y;
    sB[brow][bcol + 2] = bv.z;
    sB[brow][bcol + 3] = bv.w;
    __syncthreads();
#pragma unroll
    for (int k = 0; k < 16; ++k) {
      float a0 = sA[k][ty * 4 + 0], a1 = sA[k][ty * 4 + 1];
      float a2 = sA[k][ty * 4 + 2], a3 = sA[k][ty * 4 + 3];
      float b0 = sB[k][tx * 4 + 0], b1 = sB[k][tx * 4 + 1];
      float b2 = sB[k][tx * 4 + 2], b3 = sB[k][tx * 4 + 3];
      acc[0][0] += a0 * b0; acc[0][1] += a0 * b1; acc[0][2] += a0 * b2; acc[0][3] += a0 * b3;
      acc[1][0] += a1 * b0; acc[1][1] += a1 * b1; acc[1][2] += a1 * b2; acc[1][3] += a1 * b3;
      acc[2][0] += a2 * b0; acc[2][1] += a2 * b1; acc[2][2] += a2 * b2; acc[2][3] += a2 * b3;
      acc[3][0] += a3 * b0; acc[3][1] += a3 * b1; acc[3][2] += a3 * b2; acc[3][3] += a3 * b3;
    }
    __syncthreads();
  }
#pragma unroll
  for (int i = 0; i < 4; ++i) {
    float4 v;
    v.x = acc[i][0]; v.y = acc[i][1]; v.z = acc[i][2]; v.w = acc[i][3];
    *(float4*)(&C[(size_t)(row0 + ty * 4 + i) * F + col0 + tx * 4]) = v;
  }
}

// ---------------- attention coefficients: asrc/adst [N,4] ----------------
__global__ void attn_kernel(const float* __restrict__ h, const float* __restrict__ a_src,
                            const float* __restrict__ a_dst, float* __restrict__ attn) {
  int idx = blockIdx.x * 256 + threadIdx.x;   // n*4 + head
  if (idx >= N_NODES * HEADS) return;
  int n = idx >> 2, hh = idx & 3;
  const float* hp = h + (size_t)n * F + hh * HID;
  const float* as = a_src + hh * HID;
  const float* ad = a_dst + hh * HID;
  float s1 = 0.f, s2 = 0.f;
#pragma unroll 8
  for (int c = 0; c < HID; ++c) {
    float v = hp[c];
    s1 += v * as[c];
    s2 += v * ad[c];
  }
  attn[idx] = s1;                       // asrc
  attn[N_NODES * HEADS + idx] = s2;     // adst
}

// ---------------- per-dst softmax + weighted aggregation (no atomics) ----------------
__global__ __launch_bounds__(256) void agg_kernel(const float* __restrict__ hfeat,
                                                  const float* __restrict__ attn,
                                                  const int* __restrict__ ptr,
                                                  const int* __restrict__ csr_src,
                                                  const float* __restrict__ bias,
                                                  float* __restrict__ out) {
  int node = blockIdx.x;
  int tid = threadIdx.x;
  int beg = ptr[node], end = ptr[node + 1];
  int deg = end - beg;
  __shared__ float s_adst[4];
  __shared__ float red[256];
  const float* adst_arr = attn + N_NODES * HEADS;
  if (tid < 4) s_adst[tid] = adst_arr[node * 4 + tid];
  __syncthreads();

  // phase A: per-head max of leaky_relu(asrc[src]+adst[dst])
  int ha = tid & 3;
  float lm = -INFINITY;
  for (int p = tid; p < deg * 4; p += 256) {
    int e = p >> 2;
    int s = csr_src[beg + e];
    float v = attn[s * 4 + ha] + s_adst[ha];
    v = (v >= 0.f) ? v : NEG * v;
    lm = fmaxf(lm, v);
  }
  red[tid] = lm;
  __syncthreads();
  for (int off = 128; off >= 4; off >>= 1) {
    if (tid < off) red[tid] = fmaxf(red[tid], red[tid + off]);
    __syncthreads();
  }
  // red[h] now holds head-h max (head == tid&3 preserved by offsets %4==0)

  int hh = tid >> 6;             // head of this channel
  float m = red[hh];
  float adh = s_adst[hh];
  float acc = 0.f, denom = 0.f;
  for (int e = 0; e < deg; ++e) {
    int s = csr_src[beg + e];
    float v = attn[s * 4 + hh] + adh;
    v = (v >= 0.f) ? v : NEG * v;
    float w = expf(v - m);
    denom += w;
    acc += w * hfeat[(size_t)s * F + tid];
  }
  out[(size_t)node * F + tid] = acc / (denom + 1e-16f) + bias[tid];
}

// ---------------- GraphNorm stats ----------------
__global__ void stats_kernel(const float* __restrict__ x, float* __restrict__ colsum,
                             float* __restrict__ colsq) {
  int tid = threadIdx.x;
  int rbeg = blockIdx.x * 256;
  float s = 0.f, s2 = 0.f;
  for (int r = 0; r < 256; ++r) {
    float v = x[(size_t)(rbeg + r) * F + tid];
    s += v;
    s2 += v * v;
  }
  atomicAdd(&colsum[tid], s);
  atomicAdd(&colsq[tid], s2);
}

__global__ void norm_prelu_kernel(float* __restrict__ x, const float* __restrict__ colsum,
                                  const float* __restrict__ colsq, const float* __restrict__ w,
                                  const float* __restrict__ b, const float* __restrict__ a,
                                  const float* __restrict__ prelu_p) {
  int idx = blockIdx.x * 256 + threadIdx.x;
  int c = idx & (F - 1);
  const float invN = 1.0f / N_NODES;
  float mean = colsum[c] * invN;
  float msq = colsq[c] * invN;
  float av = a[c];
  float var = msq - (2.f * av - av * av) * mean * mean;
  float xc = x[idx] - av * mean;
  float y = w[c] * xc * rsqrtf(var + EPS) + b[c];
  float p = *prelu_p;
  x[idx] = (y >= 0.f) ? y : p * y;
}

// ---------------- mean pool by sorted batch ids ----------------
__device__ __forceinline__ int lower_bound_dev(const int* __restrict__ arr, int n, int key) {
  int lo = 0, hi = n;
  while (lo < hi) {
    int mid = (lo + hi) >> 1;
    if (arr[mid] < key) lo = mid + 1; else hi = mid;
  }
  return lo;
}

__global__ void pool_kernel(const float* __restrict__ x, const int* __restrict__ batch,
                            float* __restrict__ g) {
  int gb = blockIdx.x;
  int tid = threadIdx.x;
  int lo = lower_bound_dev(batch, N_NODES, gb);
  int hi = lower_bound_dev(batch, N_NODES, gb + 1);
  float s = 0.f;
  for (int n = lo; n < hi; ++n) s += x[(size_t)n * F + tid];
  int cnt = hi - lo;
  g[gb * F + tid] = s / fmaxf((float)cnt, 1.f);
}

// ---------------- conv1d(k=4,s=4) + avgpool(4) ----------------
__global__ void down_kernel(const float* __restrict__ g, const float* __restrict__ cw,
                            const float* __restrict__ cb, float* __restrict__ out, int cls) {
  int tid = blockIdx.x * blockDim.x + threadIdx.x;
  if (tid >= NG * 16) return;
  int ng = tid >> 4, o = tid & 15;
  float cb0 = *cb;
  float w0 = cw[0], w1 = cw[1], w2 = cw[2], w3 = cw[3];
  float acc = 0.f;
#pragma unroll
  for (int q = 0; q < 4; ++q) {
    const float* gp = g + (size_t)ng * F + (o * 4 + q) * 4;
    acc += cb0 + gp[0] * w0 + gp[1] * w1 + gp[2] * w2 + gp[3] * w3;
  }
  out[ng * (NCLS * 16) + cls * 16 + o] = acc * 0.25f;
}

extern "C" void kernel_launch(void* const* d_in, const int* in_sizes, int n_in,
                              void* d_out, int out_size, void* d_ws, size_t ws_size,
                              hipStream_t stream) {
  const float* x       = (const float*)d_in[0];
  const int*   edge    = (const int*)d_in[1];
  const int*   batch   = (const int*)d_in[2];
  const float* W1      = (const float*)d_in[3];
  const float* a_src1  = (const float*)d_in[4];
  const float* a_dst1  = (const float*)d_in[5];
  const float* b1      = (const float*)d_in[6];
  const float* W2      = (const float*)d_in[7];
  const float* a_src2  = (const float*)d_in[8];
  const float* a_dst2  = (const float*)d_in[9];
  const float* b2      = (const float*)d_in[10];
  const float* gn_w1   = (const float*)d_in[11];
  const float* gn_b1   = (const float*)d_in[12];
  const float* gn_a1   = (const float*)d_in[13];
  const float* gn_w2   = (const float*)d_in[14];
  const float* gn_b2   = (const float*)d_in[15];
  const float* gn_a2   = (const float*)d_in[16];
  const float* prelu1  = (const float*)d_in[17];
  const float* prelu2  = (const float*)d_in[18];
  const float* conv_w  = (const float*)d_in[19];
  const float* conv_b  = (const float*)d_in[20];
  float* out = (float*)d_out;

  const int E   = in_sizes[1] / (NCLS * 2);
  const int TOT = E + N_NODES;

  char* ws = (char*)d_ws;
  size_t off = 0;
  auto alloc = [&](size_t bytes) -> char* {
    char* p = ws + off;
    off += (bytes + 255) / 256 * 256;
    return p;
  };
  float* h_gemm  = (float*)alloc((size_t)N_NODES * F * 4);
  float* h_layer = (float*)alloc((size_t)N_NODES * F * 4);
  float* attn    = (float*)alloc((size_t)N_NODES * HEADS * 2 * 4);
  float* colsum  = (float*)alloc(F * 4);
  float* colsq   = (float*)alloc(F * 4);
  float* g_pool  = (float*)alloc(NG * F * 4);
  int* counts    = (int*)alloc((size_t)N_NODES * 4);
  int* csr_ptr   = (int*)alloc((size_t)(N_NODES + 8) * 4);
  int* fill      = (int*)alloc((size_t)N_NODES * 4);
  int* bsums     = (int*)alloc(256 * 4);
  int* csr_src   = (int*)alloc((size_t)TOT * 4);
  (void)ws_size; (void)n_in; (void)out_size;

  const int nblk_e = (TOT + 255) / 256;
  const dim3 gemm_grid(N_NODES / 64, F / 64);

  for (int i = 0; i < NCLS; ++i) {
    const int* srcp = edge + (size_t)i * 2 * E;
    const int* dstp = srcp + E;

    hipMemsetAsync(counts, 0, (size_t)N_NODES * 4, stream);
    hipMemsetAsync(fill,   0, (size_t)N_NODES * 4, stream);
    count_kernel<<<nblk_e, 256, 0, stream>>>(srcp, dstp, E, counts);
    scan1_kernel<<<N_NODES / 256, 256, 0, stream>>>(counts, csr_ptr, bsums);
    scan2_kernel<<<1, 64, 0, stream>>>(bsums, N_NODES / 256, csr_ptr + N_NODES);
    scan3_kernel<<<N_NODES / 256, 256, 0, stream>>>(csr_ptr, bsums);
    scatter_kernel<<<nblk_e, 256, 0, stream>>>(srcp, dstp, E, csr_ptr, fill, csr_src);

    // ---- layer 1 ----
    gemm_kernel<<<gemm_grid, 256, 0, stream>>>(x, W1 + (size_t)i * T_IN * F, h_gemm, N_NODES, T_IN);
    attn_kernel<<<(N_NODES * HEADS + 255) / 256, 256, 0, stream>>>(
        h_gemm, a_src1 + (size_t)i * HEADS * HID, a_dst1 + (size_t)i * HEADS * HID, attn);
    agg_kernel<<<N_NODES, 256, 0, stream>>>(h_gemm, attn, csr_ptr, csr_src,
                                            b1 + (size_t)i * F, h_layer);
    hipMemsetAsync(colsum, 0, F * 4, stream);
    hipMemsetAsync(colsq,  0, F * 4, stream);
    stats_kernel<<<N_NODES / 256, 256, 0, stream>>>(h_layer, colsum, colsq);
    norm_prelu_kernel<<<(N_NODES * F) / 256, 256, 0, stream>>>(
        h_layer, colsum, colsq, gn_w1 + (size_t)i * F, gn_b1 + (size_t)i * F,
        gn_a1 + (size_t)i * F, prelu1 + i);

    // ---- layer 2 ----
    gemm_kernel<<<gemm_grid, 256, 0, stream>>>(h_layer, W2 + (size_t)i * F * F, h_gemm, N_NODES, F);
    attn_kernel<<<(N_NODES * HEADS + 255) / 256, 256, 0, stream>>>(
        h_gemm, a_src2 + (size_t)i * HEADS * HID, a_dst2 + (size_t)i * HEADS * HID, attn);
    agg_kernel<<<N_NODES, 256, 0, stream>>>(h_gemm, attn, csr_ptr, csr_src,
                                            b2 + (size_t)i * F, h_layer);
    hipMemsetAsync(colsum, 0, F * 4, stream);
    hipMemsetAsync(colsq,  0, F * 4, stream);
    stats_kernel<<<N_NODES / 256, 256, 0, stream>>>(h_layer, colsum, colsq);
    norm_prelu_kernel<<<(N_NODES * F) / 256, 256, 0, stream>>>(
        h_layer, colsum, colsq, gn_w2 + (size_t)i * F, gn_b2 + (size_t)i * F,
        gn_a2 + (size_t)i * F, prelu2 + i);

    // ---- pool + down ----
    pool_kernel<<<NG, 256, 0, stream>>>(h_layer, batch + (size_t)i * N_NODES, g_pool);
    down_kernel<<<4, 256, 0, stream>>>(g_pool, conv_w + (size_t)i * 4, conv_b + i, out, i);
  }
}

// Round 2
// 984.407 us; speedup vs baseline: 2.0496x; 2.0496x over previous
//
#include <hip/hip_runtime.h>
#include <math.h>

#define N_NODES 20480
#define T_IN 128
#define F 256
#define HEADS 4
#define HID 64
#define NG 64
#define NCLS 4
#define NEG 0.2f
#define EPS 1e-5f

typedef float f32x4 __attribute__((ext_vector_type(4)));
typedef short s16x8 __attribute__((ext_vector_type(8)));

static __device__ __forceinline__ ushort f2bf(float f) {
  union { float f; unsigned u; } a; a.f = f;
  unsigned u = a.u;
  unsigned r = (u + 0x7fffu + ((u >> 16) & 1u)) >> 16;
  return (ushort)r;
}

// ---------------- CSR build ----------------
__global__ void count_kernel(const int* __restrict__ src, const int* __restrict__ dst,
                             int E, int* __restrict__ counts) {
  int e = blockIdx.x * 256 + threadIdx.x;
  int tot = E + N_NODES;
  if (e >= tot) return;
  int d = (e < E) ? dst[e] : (e - E);
  atomicAdd(&counts[d], 1);
}

__global__ void scan1_kernel(const int* __restrict__ counts, int* __restrict__ ptr,
                             int* __restrict__ bsums) {
  __shared__ int s[256];
  int tid = threadIdx.x;
  int gid = blockIdx.x * 256 + tid;
  int v = counts[gid];
  s[tid] = v;
  __syncthreads();
  for (int off = 1; off < 256; off <<= 1) {
    int t = (tid >= off) ? s[tid - off] : 0;
    __syncthreads();
    s[tid] += t;
    __syncthreads();
  }
  ptr[gid] = s[tid] - v;
  if (tid == 255) bsums[blockIdx.x] = s[255];
}

__global__ void scan2_kernel(int* __restrict__ bsums, int nb, int* __restrict__ ptr_last) {
  if (threadIdx.x == 0) {
    int acc = 0;
    for (int i = 0; i < nb; ++i) { int t = bsums[i]; bsums[i] = acc; acc += t; }
    *ptr_last = acc;
  }
}

__global__ void scan3_kernel(int* __restrict__ ptr, const int* __restrict__ bsums) {
  int gid = blockIdx.x * 256 + threadIdx.x;
  ptr[gid] += bsums[blockIdx.x];
}

__global__ void scatter_kernel(const int* __restrict__ src, const int* __restrict__ dst,
                               int E, const int* __restrict__ ptr, int* __restrict__ fill,
                               int* __restrict__ csr_src) {
  int e = blockIdx.x * 256 + threadIdx.x;
  int tot = E + N_NODES;
  if (e >= tot) return;
  int s, d;
  if (e < E) { s = src[e]; d = dst[e]; } else { s = d = e - E; }
  int pos = ptr[d] + atomicAdd(&fill[d], 1);
  csr_src[pos] = s;
}

// ---------------- fp32 -> bf16 convert ----------------
__global__ void cvt_bf16_kernel(const float* __restrict__ in, ushort* __restrict__ out, int n4) {
  int idx = blockIdx.x * 256 + threadIdx.x;
  if (idx >= n4) return;
  float4 v = *(const float4*)(&in[(size_t)idx * 4]);
  ushort4 o;
  o.x = f2bf(v.x); o.y = f2bf(v.y); o.z = f2bf(v.z); o.w = f2bf(v.w);
  *(ushort4*)(&out[(size_t)idx * 4]) = o;
}

// ---------------- MFMA GEMM: C[M,256] = A_bf16[M,K] @ B_f32[K,256] ----------------
__global__ __launch_bounds__(256) void gemm_mfma_kernel(const ushort* __restrict__ A,
                                                        const float* __restrict__ B,
                                                        float* __restrict__ C, int K) {
  __shared__ ushort sA[128][72];   // [row][k], +8 pad
  __shared__ ushort sB[128][72];   // [col][k] (B^T), +8 pad
  int tid = threadIdx.x;
  int lane = tid & 63;
  int wave = tid >> 6;
  int wr = (wave >> 1) * 64, wc = (wave & 1) * 64;
  int row0 = blockIdx.x * 128;
  int col0 = blockIdx.y * 128;
  int l15 = lane & 15, l4 = lane >> 4;
  int arow = tid >> 1, aseg = (tid & 1) * 32;
  int bcol = tid & 127, bk = (tid >> 7) * 32;
  f32x4 acc[4][4] = {};
  for (int kt = 0; kt < K; kt += 64) {
    // stage A: 32 bf16 per thread (row-major, K contiguous)
    const ushort* ap = A + (size_t)(row0 + arow) * K + kt + aseg;
#pragma unroll
    for (int i = 0; i < 4; ++i)
      *(s16x8*)(&sA[arow][aseg + i * 8]) = *(const s16x8*)(ap + i * 8);
    // stage B with on-the-fly transpose + f32->bf16
    const float* bp = B + (size_t)(kt + bk) * F + col0 + bcol;
#pragma unroll
    for (int i = 0; i < 4; ++i) {
      s16x8 wv;
#pragma unroll
      for (int kk = 0; kk < 8; ++kk) wv[kk] = (short)f2bf(bp[(size_t)(i * 8 + kk) * F]);
      *(s16x8*)(&sB[bcol][bk + i * 8]) = wv;
    }
    __syncthreads();
#pragma unroll
    for (int kh = 0; kh < 2; ++kh) {
      s16x8 af[4], bfr[4];
#pragma unroll
      for (int m = 0; m < 4; ++m)
        af[m] = *(const s16x8*)(&sA[wr + m * 16 + l15][kh * 32 + l4 * 8]);
#pragma unroll
      for (int n = 0; n < 4; ++n)
        bfr[n] = *(const s16x8*)(&sB[wc + n * 16 + l15][kh * 32 + l4 * 8]);
#pragma unroll
      for (int m = 0; m < 4; ++m)
#pragma unroll
        for (int n = 0; n < 4; ++n)
          acc[m][n] = __builtin_amdgcn_mfma_f32_16x16x32_bf16(af[m], bfr[n], acc[m][n], 0, 0, 0);
    }
    __syncthreads();
  }
#pragma unroll
  for (int m = 0; m < 4; ++m)
#pragma unroll
    for (int n = 0; n < 4; ++n) {
      int rg = row0 + wr + m * 16 + l4 * 4;
      int cg = col0 + wc + n * 16 + l15;
#pragma unroll
      for (int r = 0; r < 4; ++r)
        C[(size_t)(rg + r) * F + cg] = acc[m][n][r];
    }
}

// ---------------- attention coefficients (wave per node) ----------------
__global__ __launch_bounds__(256) void attn_kernel(const float* __restrict__ h,
                                                   const float* __restrict__ a_src,
                                                   const float* __restrict__ a_dst,
                                                   float* __restrict__ attn) {
  int wave = threadIdx.x >> 6, lane = threadIdx.x & 63;
  int n = blockIdx.x * 4 + wave;
  float4 hv = *(const float4*)(&h[(size_t)n * F + lane * 4]);
  float4 asv = *(const float4*)(&a_src[lane * 4]);
  float4 adv = *(const float4*)(&a_dst[lane * 4]);
  float s1 = hv.x * asv.x + hv.y * asv.y + hv.z * asv.z + hv.w * asv.w;
  float s2 = hv.x * adv.x + hv.y * adv.y + hv.z * adv.z + hv.w * adv.w;
  for (int m = 1; m < 16; m <<= 1) {
    s1 += __shfl_xor(s1, m);
    s2 += __shfl_xor(s2, m);
  }
  if ((lane & 15) == 0) {
    attn[n * 4 + (lane >> 4)] = s1;
    attn[N_NODES * 4 + n * 4 + (lane >> 4)] = s2;
  }
}

// ---------------- per-dst softmax + aggregation (wave per node) ----------------
__global__ __launch_bounds__(256) void agg_kernel(const float* __restrict__ hfeat,
                                                  const float* __restrict__ attn,
                                                  const int* __restrict__ ptr,
                                                  const int* __restrict__ csr_src,
                                                  const float* __restrict__ bias,
                                                  float* __restrict__ out) {
  __shared__ float w_lds[4][64][4];
  __shared__ int s_lds[4][64];
  int wave = threadIdx.x >> 6, lane = threadIdx.x & 63;
  int node = blockIdx.x * 4 + wave;
  int beg = ptr[node], end = ptr[node + 1];
  int deg = end - beg;
  const float* adst_arr = attn + N_NODES * HEADS;
  float4 ad = *(const float4*)(&adst_arr[node * 4]);

  // pass 1: per-head max over edges
  float4 mx = make_float4(-INFINITY, -INFINITY, -INFINITY, -INFINITY);
  for (int c0 = 0; c0 < deg; c0 += 64) {
    int e = c0 + lane;
    if (e < deg) {
      int s = csr_src[beg + e];
      float4 as = *(const float4*)(&attn[s * 4]);
      float vx = as.x + ad.x, vy = as.y + ad.y, vz = as.z + ad.z, vw = as.w + ad.w;
      vx = (vx >= 0.f) ? vx : NEG * vx;
      vy = (vy >= 0.f) ? vy : NEG * vy;
      vz = (vz >= 0.f) ? vz : NEG * vz;
      vw = (vw >= 0.f) ? vw : NEG * vw;
      mx.x = fmaxf(mx.x, vx); mx.y = fmaxf(mx.y, vy);
      mx.z = fmaxf(mx.z, vz); mx.w = fmaxf(mx.w, vw);
    }
  }
  for (int m = 1; m < 64; m <<= 1) {
    mx.x = fmaxf(mx.x, __shfl_xor(mx.x, m));
    mx.y = fmaxf(mx.y, __shfl_xor(mx.y, m));
    mx.z = fmaxf(mx.z, __shfl_xor(mx.z, m));
    mx.w = fmaxf(mx.w, __shfl_xor(mx.w, m));
  }

  // pass 2: exp weights (once per edge) + weighted gather
  int hh = lane >> 4;
  int c4 = lane * 4;
  float4 dsum = make_float4(0.f, 0.f, 0.f, 0.f);
  float ax = 0.f, ay = 0.f, az = 0.f, aw = 0.f;
  for (int c0 = 0; c0 < deg; c0 += 64) {
    int cnt = min(64, deg - c0);
    int e = c0 + lane;
    if (e < deg) {
      int s = csr_src[beg + e];
      float4 as = *(const float4*)(&attn[s * 4]);
      float vx = as.x + ad.x, vy = as.y + ad.y, vz = as.z + ad.z, vw = as.w + ad.w;
      vx = (vx >= 0.f) ? vx : NEG * vx;
      vy = (vy >= 0.f) ? vy : NEG * vy;
      vz = (vz >= 0.f) ? vz : NEG * vz;
      vw = (vw >= 0.f) ? vw : NEG * vw;
      float wx = __expf(vx - mx.x), wy = __expf(vy - mx.y);
      float wz = __expf(vz - mx.z), ww = __expf(vw - mx.w);
      dsum.x += wx; dsum.y += wy; dsum.z += wz; dsum.w += ww;
      s_lds[wave][lane] = s;
      w_lds[wave][lane][0] = wx; w_lds[wave][lane][1] = wy;
      w_lds[wave][lane][2] = wz; w_lds[wave][lane][3] = ww;
    }
    for (int e2 = 0; e2 < cnt; ++e2) {
      int s = s_lds[wave][e2];
      float w = w_lds[wave][e2][hh];
      float4 hv = *(const float4*)(&hfeat[(size_t)s * F + c4]);
      ax += w * hv.x; ay += w * hv.y; az += w * hv.z; aw += w * hv.w;
    }
  }
  for (int m = 1; m < 64; m <<= 1) {
    dsum.x += __shfl_xor(dsum.x, m);
    dsum.y += __shfl_xor(dsum.y, m);
    dsum.z += __shfl_xor(dsum.z, m);
    dsum.w += __shfl_xor(dsum.w, m);
  }
  float dh = (hh == 0) ? dsum.x : (hh == 1) ? dsum.y : (hh == 2) ? dsum.z : dsum.w;
  float inv = 1.f / (dh + 1e-16f);
  float4 bv = *(const float4*)(&bias[c4]);
  float4 res;
  res.x = ax * inv + bv.x; res.y = ay * inv + bv.y;
  res.z = az * inv + bv.z; res.w = aw * inv + bv.w;
  *(float4*)(&out[(size_t)node * F + c4]) = res;
}

// ---------------- GraphNorm stats ----------------
__global__ void stats_kernel(const float* __restrict__ x, float* __restrict__ colsum,
                             float* __restrict__ colsq) {
  int tid = threadIdx.x;
  int rbeg = blockIdx.x * 128;
  float s = 0.f, s2 = 0.f;
  for (int r = 0; r < 128; ++r) {
    float v = x[(size_t)(rbeg + r) * F + tid];
    s += v;
    s2 += v * v;
  }
  atomicAdd(&colsum[tid], s);
  atomicAdd(&colsq[tid], s2);
}

// ---------------- fused GraphNorm + PReLU + bf16 convert (layer-2 input) ----------------
__global__ void norm_cvt_kernel(const float* __restrict__ x, const float* __restrict__ colsum,
                                const float* __restrict__ colsq, const float* __restrict__ w,
                                const float* __restrict__ b, const float* __restrict__ a,
                                const float* __restrict__ prelu_p, ushort* __restrict__ out) {
  int idx = blockIdx.x * 256 + threadIdx.x;
  int c4 = (idx & 63) * 4;
  const float invN = 1.0f / N_NODES;
  float4 cs = *(const float4*)(&colsum[c4]);
  float4 cq = *(const float4*)(&colsq[c4]);
  float4 av = *(const float4*)(&a[c4]);
  float4 wv = *(const float4*)(&w[c4]);
  float4 bv = *(const float4*)(&b[c4]);
  float p = *prelu_p;
  float4 xv = *(const float4*)(&x[(size_t)idx * 4]);
  float o[4];
#pragma unroll
  for (int k = 0; k < 4; ++k) {
    float cs_k = (k == 0) ? cs.x : (k == 1) ? cs.y : (k == 2) ? cs.z : cs.w;
    float cq_k = (k == 0) ? cq.x : (k == 1) ? cq.y : (k == 2) ? cq.z : cq.w;
    float a_k  = (k == 0) ? av.x : (k == 1) ? av.y : (k == 2) ? av.z : av.w;
    float w_k  = (k == 0) ? wv.x : (k == 1) ? wv.y : (k == 2) ? wv.z : wv.w;
    float b_k  = (k == 0) ? bv.x : (k == 1) ? bv.y : (k == 2) ? bv.z : bv.w;
    float x_k  = (k == 0) ? xv.x : (k == 1) ? xv.y : (k == 2) ? xv.z : xv.w;
    float mean = cs_k * invN, msq = cq_k * invN;
    float var = msq - (2.f * a_k - a_k * a_k) * mean * mean;
    float y = w_k * (x_k - a_k * mean) * rsqrtf(var + EPS) + b_k;
    o[k] = (y >= 0.f) ? y : p * y;
  }
  ushort4 ov;
  ov.x = f2bf(o[0]); ov.y = f2bf(o[1]); ov.z = f2bf(o[2]); ov.w = f2bf(o[3]);
  *(ushort4*)(&out[(size_t)idx * 4]) = ov;
}

// ---------------- fused GraphNorm + PReLU + mean pool ----------------
__device__ __forceinline__ int lower_bound_dev(const int* __restrict__ arr, int n, int key) {
  int lo = 0, hi = n;
  while (lo < hi) {
    int mid = (lo + hi) >> 1;
    if (arr[mid] < key) lo = mid + 1; else hi = mid;
  }
  return lo;
}

__global__ void pool_norm_kernel(const float* __restrict__ x, const int* __restrict__ batch,
                                 const float* __restrict__ colsum, const float* __restrict__ colsq,
                                 const float* __restrict__ w, const float* __restrict__ b,
                                 const float* __restrict__ a, const float* __restrict__ prelu_p,
                                 float* __restrict__ g_pool, float* __restrict__ g_cnt) {
  int gb = blockIdx.x >> 2, part = blockIdx.x & 3;
  int tid = threadIdx.x;
  int lo = lower_bound_dev(batch, N_NODES, gb);
  int hi = lower_bound_dev(batch, N_NODES, gb + 1);
  const float invN = 1.0f / N_NODES;
  float mean = colsum[tid] * invN, msq = colsq[tid] * invN;
  float av = a[tid];
  float var = msq - (2.f * av - av * av) * mean * mean;
  float sc = w[tid] * rsqrtf(var + EPS);
  float bb = b[tid];
  float p = *prelu_p;
  float s = 0.f;
  for (int n = lo + part; n < hi; n += 4) {
    float v = x[(size_t)n * F + tid];
    float y = (v - av * mean) * sc + bb;
    s += (y >= 0.f) ? y : p * y;
  }
  atomicAdd(&g_pool[(size_t)gb * F + tid], s);
  if (part == 0 && tid == 0) g_cnt[gb] = (float)(hi - lo);
}

// ---------------- conv1d(k=4,s=4) + avgpool(4) ----------------
__global__ void down_kernel(const float* __restrict__ g, const float* __restrict__ g_cnt,
                            const float* __restrict__ cw, const float* __restrict__ cb,
                            float* __restrict__ out, int cls) {
  int tid = blockIdx.x * blockDim.x + threadIdx.x;
  if (tid >= NG * 16) return;
  int ng = tid >> 4, o = tid & 15;
  float inv = 1.f / fmaxf(g_cnt[ng], 1.f);
  float cb0 = *cb;
  float w0 = cw[0], w1 = cw[1], w2 = cw[2], w3 = cw[3];
  float acc = 0.f;
#pragma unroll
  for (int q = 0; q < 4; ++q) {
    const float* gp = g + (size_t)ng * F + (o * 4 + q) * 4;
    acc += cb0 + (gp[0] * w0 + gp[1] * w1 + gp[2] * w2 + gp[3] * w3) * inv;
  }
  out[ng * (NCLS * 16) + cls * 16 + o] = acc * 0.25f;
}

extern "C" void kernel_launch(void* const* d_in, const int* in_sizes, int n_in,
                              void* d_out, int out_size, void* d_ws, size_t ws_size,
                              hipStream_t stream) {
  const float* x       = (const float*)d_in[0];
  const int*   edge    = (const int*)d_in[1];
  const int*   batch   = (const int*)d_in[2];
  const float* W1      = (const float*)d_in[3];
  const float* a_src1  = (const float*)d_in[4];
  const float* a_dst1  = (const float*)d_in[5];
  const float* b1      = (const float*)d_in[6];
  const float* W2      = (const float*)d_in[7];
  const float* a_src2  = (const float*)d_in[8];
  const float* a_dst2  = (const float*)d_in[9];
  const float* b2      = (const float*)d_in[10];
  const float* gn_w1   = (const float*)d_in[11];
  const float* gn_b1   = (const float*)d_in[12];
  const float* gn_a1   = (const float*)d_in[13];
  const float* gn_w2   = (const float*)d_in[14];
  const float* gn_b2   = (const float*)d_in[15];
  const float* gn_a2   = (const float*)d_in[16];
  const float* prelu1  = (const float*)d_in[17];
  const float* prelu2  = (const float*)d_in[18];
  const float* conv_w  = (const float*)d_in[19];
  const float* conv_b  = (const float*)d_in[20];
  float* out = (float*)d_out;

  const int E   = in_sizes[1] / (NCLS * 2);
  const int TOT = E + N_NODES;

  char* ws = (char*)d_ws;
  size_t off = 0;
  auto alloc = [&](size_t bytes) -> char* {
    char* p = ws + off;
    off += (bytes + 255) / 256 * 256;
    return p;
  };
  float* h_gemm  = (float*)alloc((size_t)N_NODES * F * 4);
  float* h_layer = (float*)alloc((size_t)N_NODES * F * 4);
  ushort* xb     = (ushort*)alloc((size_t)N_NODES * T_IN * 2);
  ushort* h2b    = (ushort*)alloc((size_t)N_NODES * F * 2);
  float* attn    = (float*)alloc((size_t)N_NODES * HEADS * 2 * 4);
  float* colsum  = (float*)alloc(F * 4);
  float* colsq   = (float*)alloc(F * 4);
  float* g_pool  = (float*)alloc(NG * F * 4);
  float* g_cnt   = (float*)alloc(NG * 4);
  int* counts    = (int*)alloc((size_t)N_NODES * 4);
  int* csr_ptr   = (int*)alloc((size_t)(N_NODES + 8) * 4);
  int* fill      = (int*)alloc((size_t)N_NODES * 4);
  int* bsums     = (int*)alloc(256 * 4);
  int* csr_src   = (int*)alloc((size_t)TOT * 4);
  (void)ws_size; (void)n_in; (void)out_size;

  const int nblk_e = (TOT + 255) / 256;
  const dim3 gemm_grid(N_NODES / 128, 2);
  const int nwb = N_NODES / 4;   // wave-per-node grids

  // x -> bf16 once (shared by all classes)
  cvt_bf16_kernel<<<(N_NODES * T_IN / 4 + 255) / 256, 256, 0, stream>>>(x, xb, N_NODES * T_IN / 4);

  for (int i = 0; i < NCLS; ++i) {
    const int* srcp = edge + (size_t)i * 2 * E;
    const int* dstp = srcp + E;

    hipMemsetAsync(counts, 0, (size_t)N_NODES * 4, stream);
    hipMemsetAsync(fill,   0, (size_t)N_NODES * 4, stream);
    count_kernel<<<nblk_e, 256, 0, stream>>>(srcp, dstp, E, counts);
    scan1_kernel<<<N_NODES / 256, 256, 0, stream>>>(counts, csr_ptr, bsums);
    scan2_kernel<<<1, 64, 0, stream>>>(bsums, N_NODES / 256, csr_ptr + N_NODES);
    scan3_kernel<<<N_NODES / 256, 256, 0, stream>>>(csr_ptr, bsums);
    scatter_kernel<<<nblk_e, 256, 0, stream>>>(srcp, dstp, E, csr_ptr, fill, csr_src);

    // ---- layer 1 ----
    gemm_mfma_kernel<<<gemm_grid, 256, 0, stream>>>(xb, W1 + (size_t)i * T_IN * F, h_gemm, T_IN);
    attn_kernel<<<nwb, 256, 0, stream>>>(h_gemm, a_src1 + (size_t)i * F, a_dst1 + (size_t)i * F, attn);
    agg_kernel<<<nwb, 256, 0, stream>>>(h_gemm, attn, csr_ptr, csr_src, b1 + (size_t)i * F, h_layer);
    hipMemsetAsync(colsum, 0, F * 4, stream);
    hipMemsetAsync(colsq,  0, F * 4, stream);
    stats_kernel<<<N_NODES / 128, 256, 0, stream>>>(h_layer, colsum, colsq);
    norm_cvt_kernel<<<N_NODES * F / 4 / 256, 256, 0, stream>>>(
        h_layer, colsum, colsq, gn_w1 + (size_t)i * F, gn_b1 + (size_t)i * F,
        gn_a1 + (size_t)i * F, prelu1 + i, h2b);

    // ---- layer 2 ----
    gemm_mfma_kernel<<<gemm_grid, 256, 0, stream>>>(h2b, W2 + (size_t)i * F * F, h_gemm, F);
    attn_kernel<<<nwb, 256, 0, stream>>>(h_gemm, a_src2 + (size_t)i * F, a_dst2 + (size_t)i * F, attn);
    agg_kernel<<<nwb, 256, 0, stream>>>(h_gemm, attn, csr_ptr, csr_src, b2 + (size_t)i * F, h_layer);
    hipMemsetAsync(colsum, 0, F * 4, stream);
    hipMemsetAsync(colsq,  0, F * 4, stream);
    stats_kernel<<<N_NODES / 128, 256, 0, stream>>>(h_layer, colsum, colsq);

    // ---- fused norm2+prelu2+pool, then down ----
    hipMemsetAsync(g_pool, 0, NG * F * 4, stream);
    pool_norm_kernel<<<NG * 4, 256, 0, stream>>>(
        h_layer, batch + (size_t)i * N_NODES, colsum, colsq, gn_w2 + (size_t)i * F,
        gn_b2 + (size_t)i * F, gn_a2 + (size_t)i * F, prelu2 + i, g_pool, g_cnt);
    down_kernel<<<4, 256, 0, stream>>>(g_pool, g_cnt, conv_w + (size_t)i * 4, conv_b + i, out, i);
  }
}

// Round 3
// 718.748 us; speedup vs baseline: 2.8072x; 1.3696x over previous
//
#include <hip/hip_runtime.h>
#include <math.h>

#define N_NODES 20480
#define T_IN 128
#define F 256
#define HEADS 4
#define HID 64
#define NG 64
#define NCLS 4
#define NEG 0.2f
#define EPS 1e-5f
#define PTR_STRIDE (N_NODES + 64)

typedef float f32x4 __attribute__((ext_vector_type(4)));
typedef short s16x8 __attribute__((ext_vector_type(8)));

static __device__ __forceinline__ ushort f2bf(float f) {
  union { float f; unsigned u; } a; a.f = f;
  unsigned u = a.u;
  unsigned r = (u + 0x7fffu + ((u >> 16) & 1u)) >> 16;
  return (ushort)r;
}
static __device__ __forceinline__ float bf2f(ushort u) {
  union { unsigned u; float f; } a; a.u = ((unsigned)u) << 16;
  return a.f;
}

// ---------------- CSR build (all 4 classes in one pass) ----------------
__global__ void count4_kernel(const int* __restrict__ edge, int E, int* __restrict__ counts4) {
  int c = blockIdx.y;
  int e = blockIdx.x * 256 + threadIdx.x;
  int tot = E + N_NODES;
  if (e >= tot) return;
  const int* dst = edge + (size_t)c * 2 * E + E;
  int d = (e < E) ? dst[e] : (e - E);
  atomicAdd(&counts4[c * N_NODES + d], 1);
}

__global__ void scan1_kernel(const int* __restrict__ counts4, int* __restrict__ ptr4,
                             int* __restrict__ bsums) {
  __shared__ int s[256];
  int tid = threadIdx.x;
  int gid = blockIdx.x * 256 + tid;
  int c = blockIdx.x / 80;
  int n = gid - c * N_NODES;
  int v = counts4[gid];
  s[tid] = v;
  __syncthreads();
  for (int off = 1; off < 256; off <<= 1) {
    int t = (tid >= off) ? s[tid - off] : 0;
    __syncthreads();
    s[tid] += t;
    __syncthreads();
  }
  ptr4[c * PTR_STRIDE + n] = s[tid] - v;
  if (tid == 255) bsums[blockIdx.x] = s[255];
}

__global__ void scan2_kernel(int* __restrict__ bsums, int* __restrict__ ptr4) {
  int c = threadIdx.x;   // 4 threads, one class each
  if (c >= NCLS) return;
  int acc = 0;
  for (int i = 0; i < 80; ++i) {
    int t = bsums[c * 80 + i];
    bsums[c * 80 + i] = acc;
    acc += t;
  }
  ptr4[c * PTR_STRIDE + N_NODES] = acc;
}

__global__ void scan3_kernel(int* __restrict__ ptr4, const int* __restrict__ bsums) {
  int gid = blockIdx.x * 256 + threadIdx.x;
  int c = blockIdx.x / 80;
  int n = gid - c * N_NODES;
  ptr4[c * PTR_STRIDE + n] += bsums[blockIdx.x];
}

__global__ void scatter4_kernel(const int* __restrict__ edge, int E,
                                const int* __restrict__ ptr4, int* __restrict__ fill4,
                                int* __restrict__ csr_src4) {
  int c = blockIdx.y;
  int e = blockIdx.x * 256 + threadIdx.x;
  int tot = E + N_NODES;
  if (e >= tot) return;
  const int* src = edge + (size_t)c * 2 * E;
  const int* dst = src + E;
  int s, d;
  if (e < E) { s = src[e]; d = dst[e]; } else { s = d = e - E; }
  int pos = ptr4[c * PTR_STRIDE + d] + atomicAdd(&fill4[c * N_NODES + d], 1);
  csr_src4[(size_t)c * tot + pos] = s;
}

// ---------------- fp32 -> bf16 convert ----------------
__global__ void cvt_bf16_kernel(const float* __restrict__ in, ushort* __restrict__ out, int n4) {
  int idx = blockIdx.x * 256 + threadIdx.x;
  if (idx >= n4) return;
  float4 v = *(const float4*)(&in[(size_t)idx * 4]);
  ushort4 o;
  o.x = f2bf(v.x); o.y = f2bf(v.y); o.z = f2bf(v.z); o.w = f2bf(v.w);
  *(ushort4*)(&out[(size_t)idx * 4]) = o;
}

// ---------------- MFMA GEMM: C_bf16[M,256] = A_bf16[M,K] @ B_f32[K,256] ----------------
__global__ __launch_bounds__(256) void gemm_mfma_kernel(const ushort* __restrict__ A,
                                                        const float* __restrict__ B,
                                                        ushort* __restrict__ C, int K) {
  __shared__ ushort sA[128][72];   // [row][k], +8 pad
  __shared__ ushort sB[128][72];   // [col][k] (B^T), +8 pad
  int tid = threadIdx.x;
  int lane = tid & 63;
  int wave = tid >> 6;
  int wr = (wave >> 1) * 64, wc = (wave & 1) * 64;
  int row0 = blockIdx.x * 128;
  int col0 = blockIdx.y * 128;
  int l15 = lane & 15, l4 = lane >> 4;
  int arow = tid >> 1, aseg = (tid & 1) * 32;
  int bcol = tid & 127, bk = (tid >> 7) * 32;
  f32x4 acc[4][4] = {};
  for (int kt = 0; kt < K; kt += 64) {
    const ushort* ap = A + (size_t)(row0 + arow) * K + kt + aseg;
#pragma unroll
    for (int i = 0; i < 4; ++i)
      *(s16x8*)(&sA[arow][aseg + i * 8]) = *(const s16x8*)(ap + i * 8);
    const float* bp = B + (size_t)(kt + bk) * F + col0 + bcol;
#pragma unroll
    for (int i = 0; i < 4; ++i) {
      s16x8 wv;
#pragma unroll
      for (int kk = 0; kk < 8; ++kk) wv[kk] = (short)f2bf(bp[(size_t)(i * 8 + kk) * F]);
      *(s16x8*)(&sB[bcol][bk + i * 8]) = wv;
    }
    __syncthreads();
#pragma unroll
    for (int kh = 0; kh < 2; ++kh) {
      s16x8 af[4], bfr[4];
#pragma unroll
      for (int m = 0; m < 4; ++m)
        af[m] = *(const s16x8*)(&sA[wr + m * 16 + l15][kh * 32 + l4 * 8]);
#pragma unroll
      for (int n = 0; n < 4; ++n)
        bfr[n] = *(const s16x8*)(&sB[wc + n * 16 + l15][kh * 32 + l4 * 8]);
#pragma unroll
      for (int m = 0; m < 4; ++m)
#pragma unroll
        for (int n = 0; n < 4; ++n)
          acc[m][n] = __builtin_amdgcn_mfma_f32_16x16x32_bf16(af[m], bfr[n], acc[m][n], 0, 0, 0);
    }
    __syncthreads();
  }
#pragma unroll
  for (int m = 0; m < 4; ++m)
#pragma unroll
    for (int n = 0; n < 4; ++n) {
      int rg = row0 + wr + m * 16 + l4 * 4;
      int cg = col0 + wc + n * 16 + l15;
#pragma unroll
      for (int r = 0; r < 4; ++r)
        C[(size_t)(rg + r) * F + cg] = f2bf(acc[m][n][r]);
    }
}

// ---------------- attention coefficients (wave per node, bf16 h) ----------------
__global__ __launch_bounds__(256) void attn_kernel(const ushort* __restrict__ h,
                                                   const float* __restrict__ a_src,
                                                   const float* __restrict__ a_dst,
                                                   float* __restrict__ attn) {
  int wave = threadIdx.x >> 6, lane = threadIdx.x & 63;
  int n = blockIdx.x * 4 + wave;
  ushort4 hu = *(const ushort4*)(&h[(size_t)n * F + lane * 4]);
  float4 asv = *(const float4*)(&a_src[lane * 4]);
  float4 adv = *(const float4*)(&a_dst[lane * 4]);
  float h0 = bf2f(hu.x), h1 = bf2f(hu.y), h2 = bf2f(hu.z), h3 = bf2f(hu.w);
  float s1 = h0 * asv.x + h1 * asv.y + h2 * asv.z + h3 * asv.w;
  float s2 = h0 * adv.x + h1 * adv.y + h2 * adv.z + h3 * adv.w;
  for (int m = 1; m < 16; m <<= 1) {
    s1 += __shfl_xor(s1, m);
    s2 += __shfl_xor(s2, m);
  }
  if ((lane & 15) == 0) {
    attn[n * 4 + (lane >> 4)] = s1;
    attn[N_NODES * 4 + n * 4 + (lane >> 4)] = s2;
  }
}

// ---------------- per-dst softmax + aggregation (wave per node, bf16 gather) -------
__global__ __launch_bounds__(256) void agg_kernel(const ushort* __restrict__ hfeat,
                                                  const float* __restrict__ attn,
                                                  const int* __restrict__ ptr,
                                                  const int* __restrict__ csr_src,
                                                  const float* __restrict__ bias,
                                                  float* __restrict__ out) {
  __shared__ float w_lds[4][64][4];
  __shared__ int s_lds[4][64];
  int wave = threadIdx.x >> 6, lane = threadIdx.x & 63;
  int node = blockIdx.x * 4 + wave;
  int beg = ptr[node], end = ptr[node + 1];
  int deg = end - beg;
  float4 ad = *(const float4*)(&attn[N_NODES * HEADS + node * 4]);

  // chunk-0 edge values live in registers (deg <= 64 nearly always)
  int s0 = 0;
  float4 v0 = make_float4(-INFINITY, -INFINITY, -INFINITY, -INFINITY);
  if (lane < deg) {
    s0 = csr_src[beg + lane];
    float4 as = *(const float4*)(&attn[s0 * 4]);
    float vx = as.x + ad.x, vy = as.y + ad.y, vz = as.z + ad.z, vw = as.w + ad.w;
    v0.x = (vx >= 0.f) ? vx : NEG * vx;
    v0.y = (vy >= 0.f) ? vy : NEG * vy;
    v0.z = (vz >= 0.f) ? vz : NEG * vz;
    v0.w = (vw >= 0.f) ? vw : NEG * vw;
  }
  float4 mx = v0;
  for (int c0 = 64; c0 < deg; c0 += 64) {   // rare overflow path
    int e = c0 + lane;
    if (e < deg) {
      int s = csr_src[beg + e];
      float4 as = *(const float4*)(&attn[s * 4]);
      float vx = as.x + ad.x, vy = as.y + ad.y, vz = as.z + ad.z, vw = as.w + ad.w;
      vx = (vx >= 0.f) ? vx : NEG * vx;
      vy = (vy >= 0.f) ? vy : NEG * vy;
      vz = (vz >= 0.f) ? vz : NEG * vz;
      vw = (vw >= 0.f) ? vw : NEG * vw;
      mx.x = fmaxf(mx.x, vx); mx.y = fmaxf(mx.y, vy);
      mx.z = fmaxf(mx.z, vz); mx.w = fmaxf(mx.w, vw);
    }
  }
  for (int m = 1; m < 64; m <<= 1) {
    mx.x = fmaxf(mx.x, __shfl_xor(mx.x, m));
    mx.y = fmaxf(mx.y, __shfl_xor(mx.y, m));
    mx.z = fmaxf(mx.z, __shfl_xor(mx.z, m));
    mx.w = fmaxf(mx.w, __shfl_xor(mx.w, m));
  }

  int hh = lane >> 4;
  int c4 = lane * 4;
  float4 dsum = make_float4(0.f, 0.f, 0.f, 0.f);
  float ax = 0.f, ay = 0.f, az = 0.f, aw = 0.f;

  // chunk 0 from registers
  if (lane < deg) {
    float wx = __expf(v0.x - mx.x), wy = __expf(v0.y - mx.y);
    float wz = __expf(v0.z - mx.z), ww = __expf(v0.w - mx.w);
    dsum.x += wx; dsum.y += wy; dsum.z += wz; dsum.w += ww;
    s_lds[wave][lane] = s0;
    w_lds[wave][lane][0] = wx; w_lds[wave][lane][1] = wy;
    w_lds[wave][lane][2] = wz; w_lds[wave][lane][3] = ww;
  }
  {
    int cnt = min(64, deg);
    for (int e2 = 0; e2 < cnt; ++e2) {
      int s = s_lds[wave][e2];
      float w = w_lds[wave][e2][hh];
      ushort4 hu = *(const ushort4*)(&hfeat[(size_t)s * F + c4]);
      ax += w * bf2f(hu.x); ay += w * bf2f(hu.y);
      az += w * bf2f(hu.z); aw += w * bf2f(hu.w);
    }
  }
  for (int c0 = 64; c0 < deg; c0 += 64) {   // rare overflow path
    int cnt = min(64, deg - c0);
    int e = c0 + lane;
    if (e < deg) {
      int s = csr_src[beg + e];
      float4 as = *(const float4*)(&attn[s * 4]);
      float vx = as.x + ad.x, vy = as.y + ad.y, vz = as.z + ad.z, vw = as.w + ad.w;
      vx = (vx >= 0.f) ? vx : NEG * vx;
      vy = (vy >= 0.f) ? vy : NEG * vy;
      vz = (vz >= 0.f) ? vz : NEG * vz;
      vw = (vw >= 0.f) ? vw : NEG * vw;
      float wx = __expf(vx - mx.x), wy = __expf(vy - mx.y);
      float wz = __expf(vz - mx.z), ww = __expf(vw - mx.w);
      dsum.x += wx; dsum.y += wy; dsum.z += wz; dsum.w += ww;
      s_lds[wave][lane] = s;
      w_lds[wave][lane][0] = wx; w_lds[wave][lane][1] = wy;
      w_lds[wave][lane][2] = wz; w_lds[wave][lane][3] = ww;
    }
    for (int e2 = 0; e2 < cnt; ++e2) {
      int s = s_lds[wave][e2];
      float w = w_lds[wave][e2][hh];
      ushort4 hu = *(const ushort4*)(&hfeat[(size_t)s * F + c4]);
      ax += w * bf2f(hu.x); ay += w * bf2f(hu.y);
      az += w * bf2f(hu.z); aw += w * bf2f(hu.w);
    }
  }
  for (int m = 1; m < 64; m <<= 1) {
    dsum.x += __shfl_xor(dsum.x, m);
    dsum.y += __shfl_xor(dsum.y, m);
    dsum.z += __shfl_xor(dsum.z, m);
    dsum.w += __shfl_xor(dsum.w, m);
  }
  float dh = (hh == 0) ? dsum.x : (hh == 1) ? dsum.y : (hh == 2) ? dsum.z : dsum.w;
  float inv = 1.f / (dh + 1e-16f);
  float4 bv = *(const float4*)(&bias[c4]);
  float4 res;
  res.x = ax * inv + bv.x; res.y = ay * inv + bv.y;
  res.z = az * inv + bv.z; res.w = aw * inv + bv.w;
  *(float4*)(&out[(size_t)node * F + c4]) = res;
}

// ---------------- GraphNorm stats ----------------
__global__ void stats_kernel(const float* __restrict__ x, float* __restrict__ colsum,
                             float* __restrict__ colsq) {
  int tid = threadIdx.x;
  int rbeg = blockIdx.x * 128;
  float s = 0.f, s2 = 0.f;
  for (int r = 0; r < 128; ++r) {
    float v = x[(size_t)(rbeg + r) * F + tid];
    s += v;
    s2 += v * v;
  }
  atomicAdd(&colsum[tid], s);
  atomicAdd(&colsq[tid], s2);
}

// ---------------- fused GraphNorm + PReLU + bf16 convert ----------------
__global__ void norm_cvt_kernel(const float* __restrict__ x, const float* __restrict__ colsum,
                                const float* __restrict__ colsq, const float* __restrict__ w,
                                const float* __restrict__ b, const float* __restrict__ a,
                                const float* __restrict__ prelu_p, ushort* __restrict__ out) {
  int idx = blockIdx.x * 256 + threadIdx.x;
  int c4 = (idx & 63) * 4;
  const float invN = 1.0f / N_NODES;
  float4 cs = *(const float4*)(&colsum[c4]);
  float4 cq = *(const float4*)(&colsq[c4]);
  float4 av = *(const float4*)(&a[c4]);
  float4 wv = *(const float4*)(&w[c4]);
  float4 bv = *(const float4*)(&b[c4]);
  float p = *prelu_p;
  float4 xv = *(const float4*)(&x[(size_t)idx * 4]);
  float o[4];
#pragma unroll
  for (int k = 0; k < 4; ++k) {
    float cs_k = (k == 0) ? cs.x : (k == 1) ? cs.y : (k == 2) ? cs.z : cs.w;
    float cq_k = (k == 0) ? cq.x : (k == 1) ? cq.y : (k == 2) ? cq.z : cq.w;
    float a_k  = (k == 0) ? av.x : (k == 1) ? av.y : (k == 2) ? av.z : av.w;
    float w_k  = (k == 0) ? wv.x : (k == 1) ? wv.y : (k == 2) ? wv.z : wv.w;
    float b_k  = (k == 0) ? bv.x : (k == 1) ? bv.y : (k == 2) ? bv.z : bv.w;
    float x_k  = (k == 0) ? xv.x : (k == 1) ? xv.y : (k == 2) ? xv.z : xv.w;
    float mean = cs_k * invN, msq = cq_k * invN;
    float var = msq - (2.f * a_k - a_k * a_k) * mean * mean;
    float y = w_k * (x_k - a_k * mean) * rsqrtf(var + EPS) + b_k;
    o[k] = (y >= 0.f) ? y : p * y;
  }
  ushort4 ov;
  ov.x = f2bf(o[0]); ov.y = f2bf(o[1]); ov.z = f2bf(o[2]); ov.w = f2bf(o[3]);
  *(ushort4*)(&out[(size_t)idx * 4]) = ov;
}

// ---------------- fused GraphNorm + PReLU + mean pool ----------------
__device__ __forceinline__ int lower_bound_dev(const int* __restrict__ arr, int n, int key) {
  int lo = 0, hi = n;
  while (lo < hi) {
    int mid = (lo + hi) >> 1;
    if (arr[mid] < key) lo = mid + 1; else hi = mid;
  }
  return lo;
}

__global__ void pool_norm_kernel(const float* __restrict__ x, const int* __restrict__ batch,
                                 const float* __restrict__ colsum, const float* __restrict__ colsq,
                                 const float* __restrict__ w, const float* __restrict__ b,
                                 const float* __restrict__ a, const float* __restrict__ prelu_p,
                                 float* __restrict__ g_pool, float* __restrict__ g_cnt) {
  int gb = blockIdx.x >> 2, part = blockIdx.x & 3;
  int tid = threadIdx.x;
  int lo = lower_bound_dev(batch, N_NODES, gb);
  int hi = lower_bound_dev(batch, N_NODES, gb + 1);
  const float invN = 1.0f / N_NODES;
  float mean = colsum[tid] * invN, msq = colsq[tid] * invN;
  float av = a[tid];
  float var = msq - (2.f * av - av * av) * mean * mean;
  float sc = w[tid] * rsqrtf(var + EPS);
  float bb = b[tid];
  float p = *prelu_p;
  float s = 0.f;
  for (int n = lo + part; n < hi; n += 4) {
    float v = x[(size_t)n * F + tid];
    float y = (v - av * mean) * sc + bb;
    s += (y >= 0.f) ? y : p * y;
  }
  atomicAdd(&g_pool[(size_t)gb * F + tid], s);
  if (part == 0 && tid == 0) g_cnt[gb] = (float)(hi - lo);
}

// ---------------- conv1d(k=4,s=4) + avgpool(4) ----------------
__global__ void down_kernel(const float* __restrict__ g, const float* __restrict__ g_cnt,
                            const float* __restrict__ cw, const float* __restrict__ cb,
                            float* __restrict__ out, int cls) {
  int tid = blockIdx.x * blockDim.x + threadIdx.x;
  if (tid >= NG * 16) return;
  int ng = tid >> 4, o = tid & 15;
  float inv = 1.f / fmaxf(g_cnt[ng], 1.f);
  float cb0 = *cb;
  float w0 = cw[0], w1 = cw[1], w2 = cw[2], w3 = cw[3];
  float acc = 0.f;
#pragma unroll
  for (int q = 0; q < 4; ++q) {
    const float* gp = g + (size_t)ng * F + (o * 4 + q) * 4;
    acc += cb0 + (gp[0] * w0 + gp[1] * w1 + gp[2] * w2 + gp[3] * w3) * inv;
  }
  out[ng * (NCLS * 16) + cls * 16 + o] = acc * 0.25f;
}

extern "C" void kernel_launch(void* const* d_in, const int* in_sizes, int n_in,
                              void* d_out, int out_size, void* d_ws, size_t ws_size,
                              hipStream_t stream) {
  const float* x       = (const float*)d_in[0];
  const int*   edge    = (const int*)d_in[1];
  const int*   batch   = (const int*)d_in[2];
  const float* W1      = (const float*)d_in[3];
  const float* a_src1  = (const float*)d_in[4];
  const float* a_dst1  = (const float*)d_in[5];
  const float* b1      = (const float*)d_in[6];
  const float* W2      = (const float*)d_in[7];
  const float* a_src2  = (const float*)d_in[8];
  const float* a_dst2  = (const float*)d_in[9];
  const float* b2      = (const float*)d_in[10];
  const float* gn_w1   = (const float*)d_in[11];
  const float* gn_b1   = (const float*)d_in[12];
  const float* gn_a1   = (const float*)d_in[13];
  const float* gn_w2   = (const float*)d_in[14];
  const float* gn_b2   = (const float*)d_in[15];
  const float* gn_a2   = (const float*)d_in[16];
  const float* prelu1  = (const float*)d_in[17];
  const float* prelu2  = (const float*)d_in[18];
  const float* conv_w  = (const float*)d_in[19];
  const float* conv_b  = (const float*)d_in[20];
  float* out = (float*)d_out;

  const int E   = in_sizes[1] / (NCLS * 2);
  const int TOT = E + N_NODES;

  char* ws = (char*)d_ws;
  size_t off = 0;
  auto alloc = [&](size_t bytes) -> char* {
    char* p = ws + off;
    off += (bytes + 255) / 256 * 256;
    return p;
  };
  ushort* h_gemm  = (ushort*)alloc((size_t)N_NODES * F * 2);   // bf16 h
  float*  h_layer = (float*)alloc((size_t)N_NODES * F * 4);    // agg out (f32)
  ushort* xb      = (ushort*)alloc((size_t)N_NODES * T_IN * 2);
  ushort* h2b     = (ushort*)alloc((size_t)N_NODES * F * 2);
  float*  attn    = (float*)alloc((size_t)N_NODES * HEADS * 2 * 4);
  float*  colstat = (float*)alloc((size_t)NCLS * 2 * 2 * F * 4); // [cls][layer][sum|sq][F]
  float*  g_pool4 = (float*)alloc((size_t)NCLS * NG * F * 4);
  float*  g_cnt   = (float*)alloc(NG * 4);
  int* counts4    = (int*)alloc((size_t)NCLS * N_NODES * 4);
  int* ptr4       = (int*)alloc((size_t)NCLS * PTR_STRIDE * 4);
  int* fill4      = (int*)alloc((size_t)NCLS * N_NODES * 4);
  int* bsums      = (int*)alloc(512 * 4);
  int* csr_src4   = (int*)alloc((size_t)NCLS * TOT * 4);
  (void)ws_size; (void)n_in; (void)out_size;

  const int nblk_e = (TOT + 255) / 256;
  const dim3 gemm_grid(N_NODES / 128, 2);
  const int nwb = N_NODES / 4;

  // ---- upfront: bf16 x, zero accumulators, CSR for all classes ----
  cvt_bf16_kernel<<<(N_NODES * T_IN / 4 + 255) / 256, 256, 0, stream>>>(x, xb, N_NODES * T_IN / 4);
  hipMemsetAsync(counts4, 0, (size_t)NCLS * N_NODES * 4, stream);
  hipMemsetAsync(fill4,   0, (size_t)NCLS * N_NODES * 4, stream);
  hipMemsetAsync(colstat, 0, (size_t)NCLS * 2 * 2 * F * 4, stream);
  hipMemsetAsync(g_pool4, 0, (size_t)NCLS * NG * F * 4, stream);
  count4_kernel<<<dim3(nblk_e, NCLS), 256, 0, stream>>>(edge, E, counts4);
  scan1_kernel<<<NCLS * N_NODES / 256, 256, 0, stream>>>(counts4, ptr4, bsums);
  scan2_kernel<<<1, 64, 0, stream>>>(bsums, ptr4);
  scan3_kernel<<<NCLS * N_NODES / 256, 256, 0, stream>>>(ptr4, bsums);
  scatter4_kernel<<<dim3(nblk_e, NCLS), 256, 0, stream>>>(edge, E, ptr4, fill4, csr_src4);

  for (int i = 0; i < NCLS; ++i) {
    const int* ptr     = ptr4 + (size_t)i * PTR_STRIDE;
    const int* csr_src = csr_src4 + (size_t)i * TOT;
    float* cs1 = colstat + (size_t)(i * 2 + 0) * 2 * F;
    float* cq1 = cs1 + F;
    float* cs2 = colstat + (size_t)(i * 2 + 1) * 2 * F;
    float* cq2 = cs2 + F;
    float* g_pool = g_pool4 + (size_t)i * NG * F;

    // ---- layer 1 ----
    gemm_mfma_kernel<<<gemm_grid, 256, 0, stream>>>(xb, W1 + (size_t)i * T_IN * F, h_gemm, T_IN);
    attn_kernel<<<nwb, 256, 0, stream>>>(h_gemm, a_src1 + (size_t)i * F, a_dst1 + (size_t)i * F, attn);
    agg_kernel<<<nwb, 256, 0, stream>>>(h_gemm, attn, ptr, csr_src, b1 + (size_t)i * F, h_layer);
    stats_kernel<<<N_NODES / 128, 256, 0, stream>>>(h_layer, cs1, cq1);
    norm_cvt_kernel<<<N_NODES * F / 4 / 256, 256, 0, stream>>>(
        h_layer, cs1, cq1, gn_w1 + (size_t)i * F, gn_b1 + (size_t)i * F,
        gn_a1 + (size_t)i * F, prelu1 + i, h2b);

    // ---- layer 2 ----
    gemm_mfma_kernel<<<gemm_grid, 256, 0, stream>>>(h2b, W2 + (size_t)i * F * F, h_gemm, F);
    attn_kernel<<<nwb, 256, 0, stream>>>(h_gemm, a_src2 + (size_t)i * F, a_dst2 + (size_t)i * F, attn);
    agg_kernel<<<nwb, 256, 0, stream>>>(h_gemm, attn, ptr, csr_src, b2 + (size_t)i * F, h_layer);
    stats_kernel<<<N_NODES / 128, 256, 0, stream>>>(h_layer, cs2, cq2);

    // ---- fused norm2+prelu2+pool, then down ----
    pool_norm_kernel<<<NG * 4, 256, 0, stream>>>(
        h_layer, batch + (size_t)i * N_NODES, cs2, cq2, gn_w2 + (size_t)i * F,
        gn_b2 + (size_t)i * F, gn_a2 + (size_t)i * F, prelu2 + i, g_pool, g_cnt);
    down_kernel<<<4, 256, 0, stream>>>(g_pool, g_cnt, conv_w + (size_t)i * 4, conv_b + i, out, i);
  }
}